// Round 4
// baseline (179.641 us; speedup 1.0000x reference)
//
#include <hip/hip_runtime.h>

// D_MODEL=512, H=8, B=4, S=2048.
// masked_fill(-1e9) happens BEFORE abs(), so softmax(abs(scores)) is exactly
// uniform over {k : mask[b,k]==0}, independent of query/head. Whole layer
// collapses to:
//   m[b]   = mean over masked rows of value[b]
//   y[b]   = m[b] @ Wv.T + bv
//   z[b]   = y[b] @ Wo.T + bo
//   out[b,s,:] = z[b]  for all s
// Q/K/Wq/bq/Wk/bk are dead inputs.
//
// R4: single fused persistent kernel (256 blocks == 256 CUs, co-resident) with
// two manual device-scope grid barriers. Removes 2 dispatch gaps vs R3.
// Barrier counters live in ws and are zeroed by a captured hipMemsetAsync
// (ws is re-poisoned to 0xAA before every timed launch, so in-kernel init
// would race; memset node is part of the graph).

#define DM   512
#define SEQ  2048
#define NB   4
#define CH   64            // s-chunks per batch (phase 1)
#define RPB  (SEQ / CH)    // 32 rows per chunk
#define NBLK 256

// Device-scope grid barrier: writer pattern = stores; __syncthreads;
// thread0: __threadfence (publish) + atomicAdd; spin on device-scope atomic
// read; __syncthreads; __threadfence (acquire / invalidate stale lines).
__device__ __forceinline__ void grid_barrier(unsigned* cnt) {
    __syncthreads();
    if (threadIdx.x == 0) {
        __threadfence();
        atomicAdd(cnt, 1u);
        while (atomicAdd(cnt, 0u) < NBLK) __builtin_amdgcn_s_sleep(8);
    }
    __syncthreads();
    __threadfence();
}

__global__ void fused_mha_kernel(const float* __restrict__ value,
                                 const int* __restrict__ mask,
                                 const float* __restrict__ Wv,
                                 const float* __restrict__ bv,
                                 const float* __restrict__ Wo,
                                 const float* __restrict__ bo,
                                 float* __restrict__ partial,   // [NB*CH][DM]
                                 int* __restrict__ cnt_part,    // [NB*CH]
                                 float* __restrict__ y,         // [NB][DM]
                                 unsigned* __restrict__ bar,    // [2], pre-zeroed
                                 float4* __restrict__ out) {
    __shared__ float4 sh[128];
    __shared__ int shc[2];
    __shared__ alignas(16) float xs[DM];
    __shared__ float sscale;
    __shared__ alignas(16) float zloc[64];

    const int blk = blockIdx.x;
    const int t   = threadIdx.x;
    const int lane = t & 63;
    const int wave = t >> 6;

    // ---------------- Phase 1: branchless masked partial row-sums ----------
    {
        int b  = blk >> 6;          // batch
        int ch = blk & 63;          // s-chunk
        int g  = t >> 7;            // row parity group 0/1
        int c4 = t & 127;           // float4 column
        const float4* vb = (const float4*)(value + (size_t)b * SEQ * DM);
        const int*    mb = mask + b * SEQ;
        int sbeg = ch * RPB;

        float4 acc = make_float4(0.f, 0.f, 0.f, 0.f);
        int myc = 0;
#pragma unroll
        for (int it = 0; it < RPB / 2; ++it) {   // 16 independent iterations
            int s = sbeg + 2 * it + g;
            float w = (mb[s] == 0) ? 1.0f : 0.0f;
            float4 v = vb[(size_t)s * (DM / 4) + c4];
            acc.x += w * v.x; acc.y += w * v.y; acc.z += w * v.z; acc.w += w * v.w;
            myc += (w != 0.0f);
        }
        if (g == 1) sh[c4] = acc;
        if ((t & 127) == 0) shc[g] = myc;
        __syncthreads();
        if (g == 0) {
            float4 o = sh[c4];
            o.x += acc.x; o.y += acc.y; o.z += acc.z; o.w += acc.w;
            ((float4*)partial)[(size_t)blk * (DM / 4) + c4] = o;
        }
        if (t == 0) cnt_part[blk] = shc[0] + shc[1];
    }
    grid_barrier(&bar[0]);

    // ---------------- Phase 2: y[b] = (sum partial / cnt) @ Wv.T + bv ------
    if (blk < 32) {                 // 8 dim-slices x NB batches
        int b   = blk >> 3;
        int dsl = blk & 7;

        if (t < 64) {               // wave 0: count reduction
            int csum = cnt_part[b * CH + t];
#pragma unroll
            for (int off = 32; off; off >>= 1) csum += __shfl_down(csum, off);
            if (t == 0) sscale = 1.0f / (float)(csum < 1 ? 1 : csum);
        }

        const float* pb = partial + (size_t)b * CH * DM;
        float s0 = 0.f, s1 = 0.f;
#pragma unroll
        for (int c = 0; c < CH; ++c) {          // compile-time trip: pipelined
            s0 += pb[(size_t)c * DM + t];
            s1 += pb[(size_t)c * DM + t + 256];
        }
        xs[t] = s0;
        xs[t + 256] = s1;
        __syncthreads();
        float scale = sscale;

        const float4* xs4 = (const float4*)xs;
        float4 x0 = xs4[lane];
        float4 x1 = xs4[64 + lane];
#pragma unroll
        for (int jj = 0; jj < 16; ++jj) {
            int d = dsl * 64 + jj * 4 + wave;
            const float4* w4 = (const float4*)(Wv + (size_t)d * DM);
            float4 a = w4[lane];
            float4 c = w4[64 + lane];
            float sum = a.x * x0.x + a.y * x0.y + a.z * x0.z + a.w * x0.w
                      + c.x * x1.x + c.y * x1.y + c.z * x1.z + c.w * x1.w;
#pragma unroll
            for (int off = 32; off; off >>= 1) sum += __shfl_down(sum, off);
            if (lane == 0) y[b * DM + d] = sum * scale + bv[d];
        }
    }
    grid_barrier(&bar[1]);

    // ---------------- Phase 3: z slice + broadcast tile write --------------
    {
        int bx = blk & 7;           // column slice
        int sy = (blk >> 3) & 7;    // sequence slice
        int b  = blk >> 6;          // batch

        xs[t]       = y[b * DM + t];
        xs[t + 256] = y[b * DM + t + 256];
        __syncthreads();

        const float4* ys4 = (const float4*)xs;
        float4 x0 = ys4[lane];
        float4 x1 = ys4[64 + lane];
#pragma unroll
        for (int jj = 0; jj < 16; ++jj) {
            int j = jj * 4 + wave;
            int d = bx * 64 + j;
            const float4* w4 = (const float4*)(Wo + (size_t)d * DM);
            float4 a = w4[lane];
            float4 c = w4[64 + lane];
            float sum = a.x * x0.x + a.y * x0.y + a.z * x0.z + a.w * x0.w
                      + c.x * x1.x + c.y * x1.y + c.z * x1.z + c.w * x1.w;
#pragma unroll
            for (int off = 32; off; off >>= 1) sum += __shfl_down(sum, off);
            if (lane == 0) zloc[j] = sum + bo[d];
        }
        __syncthreads();

        // Write tile: rows [sy*256, sy*256+256), float4-cols [bx*16, bx*16+16).
        int j4   = t & 15;
        int srow = t >> 4;
        float4 zreg = ((const float4*)zloc)[j4];
#pragma unroll
        for (int ss = 0; ss < 16; ++ss) {
            int s = sy * 256 + ss * 16 + srow;
            out[(size_t)(b * SEQ + s) * (DM / 4) + bx * 16 + j4] = zreg;
        }
    }
}

extern "C" void kernel_launch(void* const* d_in, const int* in_sizes, int n_in,
                              void* d_out, int out_size, void* d_ws, size_t ws_size,
                              hipStream_t stream) {
    // Input order: query,key,value,mask,Wq,bq,Wk,bk,Wv,bv,Wo,bo
    const float* value = (const float*)d_in[2];
    const int*   mask  = (const int*)d_in[3];
    const float* Wv    = (const float*)d_in[8];
    const float* bv    = (const float*)d_in[9];
    const float* Wo    = (const float*)d_in[10];
    const float* bo    = (const float*)d_in[11];
    float* out = (float*)d_out;

    // ws layout: partial[NB*CH*DM] f32 | cnt_part[NB*CH] i32 | y[NB*DM] f32 | bar[2] u32
    float*    partial  = (float*)d_ws;
    int*      cnt_part = (int*)(partial + NB * CH * DM);
    float*    y        = (float*)(cnt_part + NB * CH);
    unsigned* bar      = (unsigned*)(y + NB * DM);

    hipMemsetAsync(bar, 0, 2 * sizeof(unsigned), stream);
    fused_mha_kernel<<<dim3(NBLK), dim3(256), 0, stream>>>(
        value, mask, Wv, bv, Wo, bo, partial, cnt_part, y, bar, (float4*)out);
}

// Round 5
// 130.503 us; speedup vs baseline: 1.3765x; 1.3765x over previous
//
#include <hip/hip_runtime.h>

// D_MODEL=512, H=8, B=4, S=2048.
// masked_fill(-1e9) happens BEFORE abs(), so softmax(abs(scores)) is exactly
// uniform over {k : mask[b,k]==0}, independent of query/head. Whole layer
// collapses to:
//   m[b]   = mean over masked rows of value[b]
//   y[b]   = m[b] @ Wv.T + bv
//   z[b]   = y[b] @ Wo.T + bo
//   out[b,s,:] = z[b]  for all s
// Q/K/Wq/bq/Wk/bk are dead inputs.
//
// R5: back to the R3 3-kernel structure (R4's fused grid-barrier kernel spent
// ~75us spinning on a cross-XCD atomic). Kernel A now pre-stages the chunk's
// mask words in LDS and skips mask!=0 rows with a BLOCK-UNIFORM branch
// (scalar s_cbranch, no divergence; conditions are LDS-resident so no
// memory-latency serialization) -> halves value fetch.

#define DM  512
#define SEQ 2048
#define NB  4
#define CH  64            // s-chunks per batch
#define RPB (SEQ / CH)    // 32 rows per chunk

// ---------------------------------------------------------------------------
// Kernel A: per-chunk sum of value rows where mask==0, plus count.
// grid = NB*CH = 256 blocks, 256 threads; 2 row-groups of 128 threads,
// each thread owns one float4 column slice.
// ---------------------------------------------------------------------------
__global__ void masked_partial_kernel(const float* __restrict__ value,
                                      const int* __restrict__ mask,
                                      float* __restrict__ partial,  // [NB*CH][DM]
                                      int* __restrict__ cnt_part) { // [NB*CH]
    int b  = blockIdx.x >> 6;
    int ch = blockIdx.x & 63;
    int g  = threadIdx.x >> 7;    // row parity group: 0 or 1
    int c4 = threadIdx.x & 127;   // float4 column (128 per row)
    const float4* vb = (const float4*)(value + (size_t)b * SEQ * DM);
    const int*    mb = mask + b * SEQ + ch * RPB;

    __shared__ int smask[RPB];
    if (threadIdx.x < RPB) smask[threadIdx.x] = mb[threadIdx.x];
    __syncthreads();

    float4 acc = make_float4(0.f, 0.f, 0.f, 0.f);
    int myc = 0;
    int sbeg = ch * RPB;
#pragma unroll
    for (int it = 0; it < RPB / 2; ++it) {   // 16 iterations
        int s = 2 * it + g;
        if (smask[s] == 0) {                 // block-uniform branch (LDS cond)
            float4 v = vb[(size_t)(sbeg + s) * (DM / 4) + c4];
            acc.x += v.x; acc.y += v.y; acc.z += v.z; acc.w += v.w;
            ++myc;
        }
    }

    __shared__ float4 sh[128];
    __shared__ int shc[2];
    if (g == 1) sh[c4] = acc;
    if ((threadIdx.x & 127) == 0) shc[g] = myc;
    __syncthreads();
    if (g == 0) {
        float4 o = sh[c4];
        o.x += acc.x; o.y += acc.y; o.z += acc.z; o.w += acc.w;
        ((float4*)partial)[(size_t)(b * CH + ch) * (DM / 4) + c4] = o;
    }
    if (threadIdx.x == 0) cnt_part[b * CH + ch] = shc[0] + shc[1];
}

// ---------------------------------------------------------------------------
// Kernel B: y[b][d] = (1/cnt[b]) * sum_i xsum[b][i] * Wv[d][i] + bv[d]
// grid = (8, NB), 256 threads = 4 waves; wave handles 16 output dims.
// Chunk reduction has compile-time trip count CH=64 -> fully pipelined loads.
// ---------------------------------------------------------------------------
__global__ void matvec1_kernel(const float* __restrict__ partial,  // [NB*CH][DM]
                               const int* __restrict__ cnt_part,   // [NB*CH]
                               const float* __restrict__ W,        // [DM][DM]
                               const float* __restrict__ bias,
                               float* __restrict__ y) {            // [NB][DM]
    __shared__ alignas(16) float xsf[DM];
    __shared__ float sscale;
    int b = blockIdx.y;
    int t = threadIdx.x;

    if (t < 64) {  // wave 0: count reduction
        int csum = cnt_part[b * CH + t];
#pragma unroll
        for (int off = 32; off; off >>= 1) csum += __shfl_down(csum, off);
        if (t == 0) sscale = 1.0f / (float)(csum < 1 ? 1 : csum);
    }

    {
        const float* pb = partial + (size_t)b * CH * DM;
        float s0 = 0.f, s1 = 0.f;
#pragma unroll
        for (int c = 0; c < CH; ++c) {
            s0 += pb[(size_t)c * DM + t];
            s1 += pb[(size_t)c * DM + t + 256];
        }
        xsf[t] = s0;
        xsf[t + 256] = s1;
    }
    __syncthreads();
    float scale = sscale;

    int lane = t & 63;
    int wave = t >> 6;
    const float4* xs4 = (const float4*)xsf;
    float4 x0 = xs4[lane];
    float4 x1 = xs4[64 + lane];

#pragma unroll
    for (int jj = 0; jj < 16; ++jj) {
        int d = blockIdx.x * 64 + jj * 4 + wave;
        const float4* w4 = (const float4*)(W + (size_t)d * DM);
        float4 a = w4[lane];
        float4 c = w4[64 + lane];
        float sum = a.x * x0.x + a.y * x0.y + a.z * x0.z + a.w * x0.w
                  + c.x * x1.x + c.y * x1.y + c.z * x1.z + c.w * x1.w;
#pragma unroll
        for (int off = 32; off; off >>= 1) sum += __shfl_down(sum, off);
        if (lane == 0) y[b * DM + d] = sum * scale + bias[d];
    }
}

// ---------------------------------------------------------------------------
// Kernel C: fused matvec2 + broadcast.
// grid = (8 col-slices, 8 s-slices, NB), 256 threads. Each block computes
// z[b][bx*64 .. +64] (redundant across s-slices; Wo slice L2-resident) and
// writes its 64col x 256row output tile with float4 stores.
// ---------------------------------------------------------------------------
__global__ void matvec2_bcast_kernel(const float* __restrict__ y,    // [NB][DM]
                                     const float* __restrict__ W,    // [DM][DM]
                                     const float* __restrict__ bias,
                                     float4* __restrict__ out) {
    __shared__ alignas(16) float ysf[DM];
    __shared__ alignas(16) float zloc[64];
    int bx = blockIdx.x;
    int sy = blockIdx.y;
    int b  = blockIdx.z;
    int t  = threadIdx.x;

    ysf[t]       = y[b * DM + t];
    ysf[t + 256] = y[b * DM + t + 256];
    __syncthreads();

    int lane = t & 63;
    int wave = t >> 6;
    const float4* ys4 = (const float4*)ysf;
    float4 x0 = ys4[lane];
    float4 x1 = ys4[64 + lane];

#pragma unroll
    for (int jj = 0; jj < 16; ++jj) {
        int j = jj * 4 + wave;
        int d = bx * 64 + j;
        const float4* w4 = (const float4*)(W + (size_t)d * DM);
        float4 a = w4[lane];
        float4 c = w4[64 + lane];
        float sum = a.x * x0.x + a.y * x0.y + a.z * x0.z + a.w * x0.w
                  + c.x * x1.x + c.y * x1.y + c.z * x1.z + c.w * x1.w;
#pragma unroll
        for (int off = 32; off; off >>= 1) sum += __shfl_down(sum, off);
        if (lane == 0) zloc[j] = sum + bias[d];
    }
    __syncthreads();

    // Write tile: rows [sy*256, sy*256+256), float4-cols [bx*16, bx*16+16).
    int j4   = t & 15;
    int srow = t >> 4;
    float4 zreg = ((const float4*)zloc)[j4];
#pragma unroll
    for (int ss = 0; ss < 16; ++ss) {
        int s = sy * 256 + ss * 16 + srow;
        out[(size_t)(b * SEQ + s) * (DM / 4) + bx * 16 + j4] = zreg;
    }
}

extern "C" void kernel_launch(void* const* d_in, const int* in_sizes, int n_in,
                              void* d_out, int out_size, void* d_ws, size_t ws_size,
                              hipStream_t stream) {
    // Input order: query,key,value,mask,Wq,bq,Wk,bk,Wv,bv,Wo,bo
    const float* value = (const float*)d_in[2];
    const int*   mask  = (const int*)d_in[3];
    const float* Wv    = (const float*)d_in[8];
    const float* bv    = (const float*)d_in[9];
    const float* Wo    = (const float*)d_in[10];
    const float* bo    = (const float*)d_in[11];
    float* out = (float*)d_out;

    // Workspace: partial[NB*CH*DM] | cnt_part[NB*CH] | y[NB*DM]
    float* partial  = (float*)d_ws;
    int*   cnt_part = (int*)(partial + NB * CH * DM);
    float* y        = (float*)(cnt_part + NB * CH);

    masked_partial_kernel<<<dim3(NB * CH), dim3(256), 0, stream>>>(value, mask, partial, cnt_part);
    matvec1_kernel<<<dim3(8, NB), dim3(256), 0, stream>>>(partial, cnt_part, Wv, bv, y);
    matvec2_bcast_kernel<<<dim3(8, 8, NB), dim3(256), 0, stream>>>(y, Wo, bo, (float4*)out);
}